// Round 3
// baseline (1001.686 us; speedup 1.0000x reference)
//
#include <hip/hip_runtime.h>
#include <hip/hip_bf16.h>

typedef __hip_bfloat16 bf16;

// ---- problem constants (fixed by reference file) ----
#define N_NODES 50000
#define N_EDGES 800000
#define IN_F    128
#define HID     256
#define N_CLS   10
#define N_GRAPH 256

// flags[0] = ints are int64 (read low words), flags[1] = floats are bf16
__device__ __forceinline__ int IG(const int* __restrict__ p, int i, int w) {
    return w ? p[2 * i] : p[i];
}
__device__ __forceinline__ float LF(const void* __restrict__ p, int i, int isbf) {
    return isbf ? __bfloat162float(((const bf16*)p)[i]) : ((const float*)p)[i];
}

// ---- int width detector: odd int32 words all zero -> int64 ----
__global__ __launch_bounds__(256) void k_detect_i(const int* __restrict__ ei, int* __restrict__ flags) {
    __shared__ int nz;
    if (threadIdx.x == 0) nz = 0;
    __syncthreads();
    int found = 0;
    for (int s = 0; s < 4; ++s) {
        int idx = 2 * (threadIdx.x * 4 + s) + 1;  // odd words 1..2047 (in range either way)
        if (ei[idx] != 0) found = 1;
    }
    if (found) atomicAdd(&nz, 1);
    __syncthreads();
    if (threadIdx.x == 0) flags[0] = (nz == 0) ? 1 : 0;
}

// ---- float width detector on x: fraction of 16-bit halves that decode as
// moderate-magnitude bf16. bf16 data ~99.8%, fp32 data ~55%. ----
__global__ __launch_bounds__(256) void k_detect_f(const unsigned short* __restrict__ x,
                                                  int* __restrict__ flags) {
    __shared__ int cnt;
    if (threadIdx.x == 0) cnt = 0;
    __syncthreads();
    int c = 0;
    for (int s = 0; s < 8; ++s) {
        unsigned short h = x[threadIdx.x * 8 + s];  // first 2048 halves (4KB, in range)
        int e = (h >> 7) & 0xFF;
        if (e >= 110 && e <= 135) c++;
    }
    atomicAdd(&cnt, c);
    __syncthreads();
    if (threadIdx.x == 0) flags[1] = (cnt > 1536) ? 1 : 0;  // >75% of 2048
}

// ---- degree count over dst (guarded: bad indices are dropped, never scribble) ----
__global__ __launch_bounds__(256) void k_deg(const int* __restrict__ ei, int* __restrict__ deg,
                                             const int* __restrict__ flags, int E, int N) {
    int e = blockIdx.x * 256 + threadIdx.x;
    int w = flags[0];
    if (e < E) {
        int d = IG(ei, E + e, w);
        int s = IG(ei, e, w);
        if ((unsigned)d < (unsigned)N && (unsigned)s < (unsigned)N)
            atomicAdd(&deg[d], 1);
    }
}

__global__ __launch_bounds__(256) void k_dinv(const int* __restrict__ deg, float* __restrict__ dinv,
                                              const int* __restrict__ batch, int* __restrict__ counts,
                                              const int* __restrict__ flags, int N, int G) {
    int i = blockIdx.x * 256 + threadIdx.x;
    int w = flags[0];
    if (i < N) {
        dinv[i] = rsqrtf((float)(deg[i] + 1));  // +1 self loop
        int g = IG(batch, i, w);
        if ((unsigned)g < (unsigned)G) atomicAdd(&counts[g], 1);
    }
}

// ---- exclusive scan over degrees (3 kernels; N <= 65536) ----
__global__ __launch_bounds__(256) void k_scan1(const int* __restrict__ deg, int* __restrict__ rowptr,
                                               int* __restrict__ blockSum, int N) {
    __shared__ int s[256];
    int t = threadIdx.x;
    int i = blockIdx.x * 256 + t;
    int v = (i < N) ? deg[i] : 0;
    s[t] = v;
    __syncthreads();
    for (int off = 1; off < 256; off <<= 1) {
        int add = (t >= off) ? s[t - off] : 0;
        __syncthreads();
        s[t] += add;
        __syncthreads();
    }
    if (i < N) rowptr[i] = s[t] - v;  // exclusive
    if (t == 255) blockSum[blockIdx.x] = s[t];
}

__global__ __launch_bounds__(256) void k_scan2(const int* __restrict__ blockSum, int* __restrict__ blockOff, int nb) {
    __shared__ int s[256];
    int t = threadIdx.x;
    int v = (t < nb) ? blockSum[t] : 0;
    s[t] = v;
    __syncthreads();
    for (int off = 1; off < 256; off <<= 1) {
        int add = (t >= off) ? s[t - off] : 0;
        __syncthreads();
        s[t] += add;
        __syncthreads();
    }
    blockOff[t] = s[t] - v;
}

__global__ __launch_bounds__(256) void k_scan3(int* __restrict__ rowptr, const int* __restrict__ blockOff,
                                               int N, int* __restrict__ total) {
    int i = blockIdx.x * 256 + threadIdx.x;
    if (i < N) rowptr[i] += blockOff[blockIdx.x];
    if (i == 0) rowptr[N] = total[0];  // total filled edges (== E on well-formed data)
}

// count of valid edges -> rowptr[N]
__global__ __launch_bounds__(256) void k_count_valid(const int* __restrict__ ei, int* __restrict__ total,
                                                     const int* __restrict__ flags, int E, int N) {
    int e = blockIdx.x * 256 + threadIdx.x;
    int w = flags[0];
    if (e < E) {
        int d = IG(ei, E + e, w);
        int s = IG(ei, e, w);
        if ((unsigned)d < (unsigned)N && (unsigned)s < (unsigned)N)
            atomicAdd(total, 1);
    }
}

// ---- CSR fill (guarded identically to k_deg so cursor==deg) ----
__global__ __launch_bounds__(256) void k_fill(const int* __restrict__ ei, const int* __restrict__ rowptr,
                                              int* __restrict__ cursor, int* __restrict__ col,
                                              const int* __restrict__ flags, int E, int N) {
    int e = blockIdx.x * 256 + threadIdx.x;
    int w = flags[0];
    if (e < E) {
        int d = IG(ei, E + e, w);
        int s = IG(ei, e, w);
        if ((unsigned)d < (unsigned)N && (unsigned)s < (unsigned)N) {
            int pos = atomicAdd(&cursor[d], 1);
            col[rowptr[d] + pos] = s;
        }
    }
}

// ---- fp32 tiled GEMM: C[M x Nc] = A[M x K] @ B[K x Nc] ----
// A: input-dtype if aFlagged else fp32; B: input-dtype (weights)
__global__ __launch_bounds__(256) void k_gemm(const void* __restrict__ A, const void* __restrict__ B,
                                              float* __restrict__ C, const int* __restrict__ flags,
                                              int aFlagged, int M, int K, int Nc) {
    __shared__ float As[16][64];  // As[k][m]
    __shared__ float Bs[16][64];  // Bs[k][n]
    int fb = flags[1];
    int fa = aFlagged ? fb : 0;
    int bm = blockIdx.x * 64;
    int bn = blockIdx.y * 64;
    int t = threadIdx.x;
    int tx = t & 15, ty = t >> 4;
    float acc[4][4] = {};
    for (int k0 = 0; k0 < K; k0 += 16) {
#pragma unroll
        for (int i = 0; i < 4; ++i) {
            int j = t + i * 256;          // 0..1023
            int m = j >> 4, kk = j & 15;  // 64 x 16
            int gm = bm + m;
            float v = 0.f;
            if (gm < M) v = LF(A, gm * K + k0 + kk, fa);
            As[kk][m] = v;
        }
#pragma unroll
        for (int i = 0; i < 4; ++i) {
            int j = t + i * 256;
            int kk = j >> 6, n = j & 63;  // 16 x 64
            Bs[kk][n] = LF(B, (k0 + kk) * Nc + bn + n, fb);
        }
        __syncthreads();
#pragma unroll
        for (int kk = 0; kk < 16; ++kk) {
            float4 a = *(const float4*)&As[kk][ty * 4];
            float4 b = *(const float4*)&Bs[kk][tx * 4];
            acc[0][0] = fmaf(a.x, b.x, acc[0][0]);
            acc[0][1] = fmaf(a.x, b.y, acc[0][1]);
            acc[0][2] = fmaf(a.x, b.z, acc[0][2]);
            acc[0][3] = fmaf(a.x, b.w, acc[0][3]);
            acc[1][0] = fmaf(a.y, b.x, acc[1][0]);
            acc[1][1] = fmaf(a.y, b.y, acc[1][1]);
            acc[1][2] = fmaf(a.y, b.z, acc[1][2]);
            acc[1][3] = fmaf(a.y, b.w, acc[1][3]);
            acc[2][0] = fmaf(a.z, b.x, acc[2][0]);
            acc[2][1] = fmaf(a.z, b.y, acc[2][1]);
            acc[2][2] = fmaf(a.z, b.z, acc[2][2]);
            acc[2][3] = fmaf(a.z, b.w, acc[2][3]);
            acc[3][0] = fmaf(a.w, b.x, acc[3][0]);
            acc[3][1] = fmaf(a.w, b.y, acc[3][1]);
            acc[3][2] = fmaf(a.w, b.z, acc[3][2]);
            acc[3][3] = fmaf(a.w, b.w, acc[3][3]);
        }
        __syncthreads();
    }
#pragma unroll
    for (int i = 0; i < 4; ++i) {
        int gm = bm + ty * 4 + i;
        if (gm < M) {
            float4 o = make_float4(acc[i][0], acc[i][1], acc[i][2], acc[i][3]);
            *(float4*)&C[gm * Nc + bn + tx * 4] = o;
        }
    }
}

// ---- aggregation layer 1: H1 = relu(di*(sum_nb XW[c]*dc + XW[i]*di) + b1) ----
// one wave per node, lane = 4 features (HID == 256)
__global__ __launch_bounds__(256) void k_agg_relu(const float4* __restrict__ XW, const int* __restrict__ rowptr,
                                                  const int* __restrict__ col, const float* __restrict__ dinv,
                                                  const void* __restrict__ bias, const int* __restrict__ flags,
                                                  float4* __restrict__ Hout, int N) {
    int lane = threadIdx.x & 63;
    int i = (blockIdx.x * 256 + threadIdx.x) >> 6;
    if (i >= N) return;
    int fb = flags[1];
    float di = dinv[i];
    float4 acc = XW[i * 64 + lane];  // self loop term (one dinv_i here, one at the end)
    acc.x *= di; acc.y *= di; acc.z *= di; acc.w *= di;
    int s = rowptr[i], e = rowptr[i + 1];
    for (int j = s; j < e; ++j) {
        int c = col[j];
        if ((unsigned)c >= (unsigned)N) continue;
        float dc = dinv[c];
        float4 v = XW[c * 64 + lane];
        acc.x = fmaf(v.x, dc, acc.x);
        acc.y = fmaf(v.y, dc, acc.y);
        acc.z = fmaf(v.z, dc, acc.z);
        acc.w = fmaf(v.w, dc, acc.w);
    }
    float4 b;
    b.x = LF(bias, lane * 4 + 0, fb); b.y = LF(bias, lane * 4 + 1, fb);
    b.z = LF(bias, lane * 4 + 2, fb); b.w = LF(bias, lane * 4 + 3, fb);
    float4 r;
    r.x = fmaxf(fmaf(acc.x, di, b.x), 0.f);
    r.y = fmaxf(fmaf(acc.y, di, b.y), 0.f);
    r.z = fmaxf(fmaf(acc.z, di, b.z), 0.f);
    r.w = fmaxf(fmaf(acc.w, di, b.w), 0.f);
    Hout[i * 64 + lane] = r;
}

// ---- aggregation layer 2 fused with mean-pool numerator ----
__global__ __launch_bounds__(256) void k_agg_pool(const float4* __restrict__ XW, const int* __restrict__ rowptr,
                                                  const int* __restrict__ col, const float* __restrict__ dinv,
                                                  const void* __restrict__ bias, const int* __restrict__ batch,
                                                  float* __restrict__ pool, const int* __restrict__ flags,
                                                  int N, int H, int G) {
    int lane = threadIdx.x & 63;
    int i = (blockIdx.x * 256 + threadIdx.x) >> 6;
    if (i >= N) return;
    int w = flags[0];
    int fb = flags[1];
    float di = dinv[i];
    float4 acc = XW[i * 64 + lane];
    acc.x *= di; acc.y *= di; acc.z *= di; acc.w *= di;
    int s = rowptr[i], e = rowptr[i + 1];
    for (int j = s; j < e; ++j) {
        int c = col[j];
        if ((unsigned)c >= (unsigned)N) continue;
        float dc = dinv[c];
        float4 v = XW[c * 64 + lane];
        acc.x = fmaf(v.x, dc, acc.x);
        acc.y = fmaf(v.y, dc, acc.y);
        acc.z = fmaf(v.z, dc, acc.z);
        acc.w = fmaf(v.w, dc, acc.w);
    }
    float4 b;
    b.x = LF(bias, lane * 4 + 0, fb); b.y = LF(bias, lane * 4 + 1, fb);
    b.z = LF(bias, lane * 4 + 2, fb); b.w = LF(bias, lane * 4 + 3, fb);
    float4 r;
    r.x = fmaf(acc.x, di, b.x);
    r.y = fmaf(acc.y, di, b.y);
    r.z = fmaf(acc.z, di, b.z);
    r.w = fmaf(acc.w, di, b.w);
    int g = IG(batch, i, w);
    if ((unsigned)g >= (unsigned)G) return;
    float* p = pool + (size_t)g * H + lane * 4;
    atomicAdd(p + 0, r.x);
    atomicAdd(p + 1, r.y);
    atomicAdd(p + 2, r.z);
    atomicAdd(p + 3, r.w);
}

// ---- classifier: out[g][c] = (pool[g]/count[g]) @ Wlin + blin ----
// Output dtype follows the detected float width: fp32 normally, bf16 if the
// inputs were bf16 (reference output dtype == input float dtype).
__global__ void k_final(const float* __restrict__ pool, const int* __restrict__ counts,
                        const void* __restrict__ Wlin, const void* __restrict__ blin,
                        const int* __restrict__ flags, void* __restrict__ outv, int H, int C) {
    __shared__ float p[HID];
    int g = blockIdx.x;
    int t = threadIdx.x;
    int fb = flags[1];
    float inv = 1.f / fmaxf((float)counts[g], 1.f);
    p[t] = pool[(size_t)g * H + t] * inv;
    __syncthreads();
    if (t < C) {
        float s = LF(blin, t, fb);
        for (int f = 0; f < H; ++f) s = fmaf(p[f], LF(Wlin, f * C + t, fb), s);
        if (fb) ((bf16*)outv)[g * C + t] = __float2bfloat16(s);
        else    ((float*)outv)[g * C + t] = s;
    }
}

extern "C" void kernel_launch(void* const* d_in, const int* in_sizes, int n_in,
                              void* d_out, int out_size, void* d_ws, size_t ws_size,
                              hipStream_t stream) {
    (void)n_in; (void)ws_size; (void)in_sizes; (void)out_size;
    const void* x    = d_in[0];
    const int*  ei   = (const int*)d_in[1];
    const int*  batch= (const int*)d_in[2];
    const void* W1   = d_in[3];
    const void* b1   = d_in[4];
    const void* W2   = d_in[5];
    const void* b2   = d_in[6];
    const void* Wl   = d_in[7];
    const void* bl   = d_in[8];

    const int N = N_NODES, E = N_EDGES, F = IN_F, H = HID, C = N_CLS, G = N_GRAPH;

    char* ws = (char*)d_ws;
    size_t off = 0;
    auto alloc = [&](size_t bytes) -> void* {
        void* p = ws + off;
        off += (bytes + 511) & ~(size_t)511;
        return p;
    };
    float* bufA   = (float*)alloc((size_t)N * H * 4);  // XW1, then XW2
    float* bufB   = (float*)alloc((size_t)N * H * 4);  // H1
    int*   deg    = (int*)alloc((size_t)N * 4);        // zero region starts here
    int*   cursor = (int*)alloc((size_t)N * 4);
    int*   counts = (int*)alloc((size_t)G * 4);
    int*   total  = (int*)alloc(512);
    float* pool   = (float*)alloc((size_t)G * H * 4);  // zero region ends here
    size_t zero_bytes = (size_t)((char*)pool + (size_t)G * H * 4 - (char*)deg);
    float* dinv   = (float*)alloc((size_t)N * 4);
    int*   rowptr = (int*)alloc((size_t)(N + 1) * 4);
    int*   blockSum = (int*)alloc(256 * 4);
    int*   blockOff = (int*)alloc(256 * 4);
    int*   flags  = (int*)alloc(512);
    int*   col    = (int*)alloc((size_t)E * 4);

    hipMemsetAsync(deg, 0, zero_bytes, stream);

    int nbE = (E + 255) / 256;
    int nbN = (N + 255) / 256;

    k_detect_i<<<1, 256, 0, stream>>>(ei, flags);
    k_detect_f<<<1, 256, 0, stream>>>((const unsigned short*)x, flags);
    k_deg<<<nbE, 256, 0, stream>>>(ei, deg, flags, E, N);
    k_count_valid<<<nbE, 256, 0, stream>>>(ei, total, flags, E, N);
    k_dinv<<<nbN, 256, 0, stream>>>(deg, dinv, batch, counts, flags, N, G);
    k_scan1<<<nbN, 256, 0, stream>>>(deg, rowptr, blockSum, N);
    k_scan2<<<1, 256, 0, stream>>>(blockSum, blockOff, nbN);
    k_scan3<<<nbN, 256, 0, stream>>>(rowptr, blockOff, N, total);
    k_fill<<<nbE, 256, 0, stream>>>(ei, rowptr, cursor, col, flags, E, N);

    dim3 gemmGrid((N + 63) / 64, H / 64);
    k_gemm<<<gemmGrid, 256, 0, stream>>>(x, W1, bufA, flags, 1, N, F, H);

    int nbAgg = (N + 3) / 4;
    k_agg_relu<<<nbAgg, 256, 0, stream>>>((const float4*)bufA, rowptr, col, dinv, b1, flags, (float4*)bufB, N);

    k_gemm<<<gemmGrid, 256, 0, stream>>>(bufB, W2, bufA, flags, 0, N, H, H);

    k_agg_pool<<<nbAgg, 256, 0, stream>>>((const float4*)bufA, rowptr, col, dinv, b2, batch, pool, flags, N, H, G);

    k_final<<<G, H, 0, stream>>>(pool, counts, Wl, bl, flags, d_out, H, C);
}

// Round 4
// 534.705 us; speedup vs baseline: 1.8733x; 1.8733x over previous
//
#include <hip/hip_runtime.h>
#include <hip/hip_bf16.h>

typedef __hip_bfloat16 bf16;
typedef __attribute__((ext_vector_type(8))) short short8;
typedef __attribute__((ext_vector_type(4))) float f32x4;

// ---- problem constants (fixed by reference file) ----
#define N_NODES 50000
#define N_EDGES 800000
#define IN_F    128
#define HID     256
#define N_CLS   10
#define N_GRAPH 256

// flags[0] = ints are int64 (read low words), flags[1] = floats are bf16
__device__ __forceinline__ int IG(const int* __restrict__ p, int i, int w) {
    return w ? p[2 * i] : p[i];
}
__device__ __forceinline__ float LF(const void* __restrict__ p, int i, int isbf) {
    return isbf ? __bfloat162float(((const bf16*)p)[i]) : ((const float*)p)[i];
}
__device__ __forceinline__ float b2f(unsigned short h) {
    union { unsigned u; float f; } c; c.u = ((unsigned)h) << 16; return c.f;
}
__device__ __forceinline__ unsigned short f2b(float x) {
    bf16 h = __float2bfloat16(x);
    union { bf16 b; unsigned short u; } c; c.b = h; return c.u;
}

// ---- int width detector: odd int32 words all zero -> int64 ----
__global__ __launch_bounds__(256) void k_detect_i(const int* __restrict__ ei, int* __restrict__ flags) {
    __shared__ int nz;
    if (threadIdx.x == 0) nz = 0;
    __syncthreads();
    int found = 0;
    for (int s = 0; s < 4; ++s) {
        int idx = 2 * (threadIdx.x * 4 + s) + 1;
        if (ei[idx] != 0) found = 1;
    }
    if (found) atomicAdd(&nz, 1);
    __syncthreads();
    if (threadIdx.x == 0) flags[0] = (nz == 0) ? 1 : 0;
}

// ---- float width detector on x ----
__global__ __launch_bounds__(256) void k_detect_f(const unsigned short* __restrict__ x,
                                                  int* __restrict__ flags) {
    __shared__ int cnt;
    if (threadIdx.x == 0) cnt = 0;
    __syncthreads();
    int c = 0;
    for (int s = 0; s < 8; ++s) {
        unsigned short h = x[threadIdx.x * 8 + s];
        int e = (h >> 7) & 0xFF;
        if (e >= 110 && e <= 135) c++;
    }
    atomicAdd(&cnt, c);
    __syncthreads();
    if (threadIdx.x == 0) flags[1] = (cnt > 1536) ? 1 : 0;
}

// ---- degree count over dst ----
__global__ __launch_bounds__(256) void k_deg(const int* __restrict__ ei, int* __restrict__ deg,
                                             const int* __restrict__ flags, int E, int N) {
    int e = blockIdx.x * 256 + threadIdx.x;
    int w = flags[0];
    if (e < E) {
        int d = IG(ei, E + e, w);
        int s = IG(ei, e, w);
        if ((unsigned)d < (unsigned)N && (unsigned)s < (unsigned)N)
            atomicAdd(&deg[d], 1);
    }
}

__global__ __launch_bounds__(256) void k_dinv(const int* __restrict__ deg, float* __restrict__ dinv,
                                              const int* __restrict__ batch, int* __restrict__ counts,
                                              const int* __restrict__ flags, int N, int G) {
    int i = blockIdx.x * 256 + threadIdx.x;
    int w = flags[0];
    if (i < N) {
        dinv[i] = rsqrtf((float)(deg[i] + 1));  // +1 self loop
        int g = IG(batch, i, w);
        if ((unsigned)g < (unsigned)G) atomicAdd(&counts[g], 1);
    }
}

// ---- exclusive scan over degrees ----
__global__ __launch_bounds__(256) void k_scan1(const int* __restrict__ deg, int* __restrict__ rowptr,
                                               int* __restrict__ blockSum, int N) {
    __shared__ int s[256];
    int t = threadIdx.x;
    int i = blockIdx.x * 256 + t;
    int v = (i < N) ? deg[i] : 0;
    s[t] = v;
    __syncthreads();
    for (int off = 1; off < 256; off <<= 1) {
        int add = (t >= off) ? s[t - off] : 0;
        __syncthreads();
        s[t] += add;
        __syncthreads();
    }
    if (i < N) rowptr[i] = s[t] - v;
    if (t == 255) blockSum[blockIdx.x] = s[t];
}

__global__ __launch_bounds__(256) void k_scan2(const int* __restrict__ blockSum, int* __restrict__ blockOff,
                                               int* __restrict__ total, int nb) {
    __shared__ int s[256];
    int t = threadIdx.x;
    int v = (t < nb) ? blockSum[t] : 0;
    s[t] = v;
    __syncthreads();
    for (int off = 1; off < 256; off <<= 1) {
        int add = (t >= off) ? s[t - off] : 0;
        __syncthreads();
        s[t] += add;
        __syncthreads();
    }
    blockOff[t] = s[t] - v;
    if (t == 255) total[0] = s[255];
}

__global__ __launch_bounds__(256) void k_scan3(int* __restrict__ rowptr, const int* __restrict__ blockOff,
                                               int N, const int* __restrict__ total) {
    int i = blockIdx.x * 256 + threadIdx.x;
    if (i < N) rowptr[i] += blockOff[blockIdx.x];
    if (i == 0) rowptr[N] = total[0];
}

// exclusive scan of per-graph counts -> gstart (single block, G==256)
__global__ __launch_bounds__(256) void k_scang(const int* __restrict__ counts, int* __restrict__ gstart) {
    __shared__ int s[256];
    int t = threadIdx.x;
    int v = counts[t];
    s[t] = v;
    __syncthreads();
    for (int off = 1; off < 256; off <<= 1) {
        int add = (t >= off) ? s[t - off] : 0;
        __syncthreads();
        s[t] += add;
        __syncthreads();
    }
    gstart[t] = s[t] - v;
}

// ---- CSR fill ----
__global__ __launch_bounds__(256) void k_fill(const int* __restrict__ ei, const int* __restrict__ rowptr,
                                              int* __restrict__ cursor, int* __restrict__ col,
                                              const int* __restrict__ flags, int E, int N) {
    int e = blockIdx.x * 256 + threadIdx.x;
    int w = flags[0];
    if (e < E) {
        int d = IG(ei, E + e, w);
        int s = IG(ei, e, w);
        if ((unsigned)d < (unsigned)N && (unsigned)s < (unsigned)N) {
            int pos = atomicAdd(&cursor[d], 1);
            col[rowptr[d] + pos] = s;
        }
    }
}

// ---- convert float table (fp32 or bf16 per flags) to bf16, 4 elems/thread ----
__global__ __launch_bounds__(256) void k_cvt4(const void* __restrict__ in, unsigned short* __restrict__ out,
                                              const int* __restrict__ flags, int n4) {
    int i = blockIdx.x * 256 + threadIdx.x;
    if (i >= n4) return;
    if (flags[1]) {
        ((ushort4*)out)[i] = ((const ushort4*)in)[i];
    } else {
        float4 v = ((const float4*)in)[i];
        ushort4 o;
        o.x = f2b(v.x); o.y = f2b(v.y); o.z = f2b(v.z); o.w = f2b(v.w);
        ((ushort4*)out)[i] = o;
    }
}

// ---- convert + transpose weight W[K x 256] -> Wt[256 x K] bf16 ----
__global__ __launch_bounds__(256) void k_cvtT(const void* __restrict__ in, unsigned short* __restrict__ out,
                                              const int* __restrict__ flags, int K, int kshift) {
    int i = blockIdx.x * 256 + threadIdx.x;  // output index, [n][k]
    if (i >= K * 256) return;
    int n = i >> kshift;
    int k = i & (K - 1);
    out[i] = f2b(LF(in, k * 256 + n, flags[1]));
}

// ---- bf16 MFMA GEMM: C[M x 256] = A[M x K] @ B[K x 256]; Bt is B transposed [256 x K]
// 64-row x 256-col block tile; 4 waves in 2x2 (32 rows x 128 cols each);
// LDS rows padded to 40 bf16 (80 B) for conflict-free ds_read_b128.
__global__ __launch_bounds__(256) void k_gemm(const unsigned short* __restrict__ A,
                                              const unsigned short* __restrict__ Bt,
                                              unsigned short* __restrict__ C, int M, int K) {
    __shared__ unsigned short As[64 * 40];
    __shared__ unsigned short Bs[256 * 40];
    int t = threadIdx.x;
    int lane = t & 63;
    int w = t >> 6;
    int wr = w >> 1, wc = w & 1;
    int bm = blockIdx.x * 64;
    int l15 = lane & 15, quad = lane >> 4;
    f32x4 acc[2][8];
#pragma unroll
    for (int i = 0; i < 2; ++i)
#pragma unroll
        for (int j = 0; j < 8; ++j) acc[i][j] = (f32x4){0.f, 0.f, 0.f, 0.f};

    for (int k0 = 0; k0 < K; k0 += 32) {
        {   // stage A: 64 rows x 32 k; thread -> (m = t>>2, chunk c = t&3)
            int m = t >> 2, c = t & 3;
            int gm = bm + m;
            uint4 v = make_uint4(0u, 0u, 0u, 0u);
            if (gm < M) v = *(const uint4*)&A[(size_t)gm * K + k0 + c * 8];
            *(uint4*)&As[m * 40 + c * 8] = v;
        }
#pragma unroll
        for (int i = 0; i < 4; ++i) {  // stage B: 256 n x 32 k
            int cid = t + 256 * i;
            int n = cid >> 2, c = cid & 3;
            uint4 v = *(const uint4*)&Bt[(size_t)n * K + k0 + c * 8];
            *(uint4*)&Bs[n * 40 + c * 8] = v;
        }
        __syncthreads();
        short8 a0 = *(const short8*)&As[(wr * 32 + l15) * 40 + quad * 8];
        short8 a1 = *(const short8*)&As[(wr * 32 + 16 + l15) * 40 + quad * 8];
#pragma unroll
        for (int tt = 0; tt < 8; ++tt) {
            short8 b = *(const short8*)&Bs[(wc * 128 + tt * 16 + l15) * 40 + quad * 8];
            acc[0][tt] = __builtin_amdgcn_mfma_f32_16x16x32_bf16(a0, b, acc[0][tt], 0, 0, 0);
            acc[1][tt] = __builtin_amdgcn_mfma_f32_16x16x32_bf16(a1, b, acc[1][tt], 0, 0, 0);
        }
        __syncthreads();
    }
    // C/D layout: col = lane&15, row = quad*4 + r
#pragma unroll
    for (int sa = 0; sa < 2; ++sa)
#pragma unroll
        for (int tt = 0; tt < 8; ++tt)
#pragma unroll
            for (int r = 0; r < 4; ++r) {
                int row = bm + wr * 32 + sa * 16 + quad * 4 + r;
                int colc = wc * 128 + tt * 16 + l15;
                if (row < M) C[(size_t)row * 256 + colc] = f2b(acc[sa][tt][r]);
            }
}

// ---- aggregation: Hout = [relu](di*(sum_nb XW[c]*dc + XW[i]*di) + bias), bf16 tables ----
// one wave per node, lane = 4 features (HID == 256)
__global__ __launch_bounds__(256) void k_agg(const unsigned short* __restrict__ XW,
                                             const int* __restrict__ rowptr, const int* __restrict__ col,
                                             const float* __restrict__ dinv, const void* __restrict__ bias,
                                             const int* __restrict__ flags, unsigned short* __restrict__ Hout,
                                             int N, int relu) {
    int lane = threadIdx.x & 63;
    int i = (blockIdx.x * 256 + threadIdx.x) >> 6;
    if (i >= N) return;
    int fb = flags[1];
    float di = dinv[i];
    ushort4 sv = *(const ushort4*)&XW[(size_t)i * 256 + lane * 4];
    float ax = b2f(sv.x) * di, ay = b2f(sv.y) * di, az = b2f(sv.z) * di, aw = b2f(sv.w) * di;
    int s = rowptr[i], e = rowptr[i + 1];
    for (int j = s; j < e; ++j) {
        int c = col[j];
        if ((unsigned)c >= (unsigned)N) continue;
        float dc = dinv[c];
        ushort4 v = *(const ushort4*)&XW[(size_t)c * 256 + lane * 4];
        ax = fmaf(b2f(v.x), dc, ax);
        ay = fmaf(b2f(v.y), dc, ay);
        az = fmaf(b2f(v.z), dc, az);
        aw = fmaf(b2f(v.w), dc, aw);
    }
    float bx = LF(bias, lane * 4 + 0, fb), by = LF(bias, lane * 4 + 1, fb);
    float bz = LF(bias, lane * 4 + 2, fb), bw = LF(bias, lane * 4 + 3, fb);
    float rx = fmaf(ax, di, bx), ry = fmaf(ay, di, by);
    float rz = fmaf(az, di, bz), rw = fmaf(aw, di, bw);
    if (relu) {
        rx = fmaxf(rx, 0.f); ry = fmaxf(ry, 0.f);
        rz = fmaxf(rz, 0.f); rw = fmaxf(rw, 0.f);
    }
    ushort4 o;
    o.x = f2b(rx); o.y = f2b(ry); o.z = f2b(rz); o.w = f2b(rw);
    *(ushort4*)&Hout[(size_t)i * 256 + lane * 4] = o;
}

// ---- segment-mean pool over sorted batch ranges: one block per graph ----
// 256 threads: (sub = t>>6) handles rows i = start+sub, +4...; lane*4 features; LDS reduce.
__global__ __launch_bounds__(256) void k_pool(const unsigned short* __restrict__ H2,
                                              const int* __restrict__ gstart, const int* __restrict__ counts,
                                              float* __restrict__ pooled) {
    __shared__ float red[4][256];
    int g = blockIdx.x, t = threadIdx.x;
    int sub = t >> 6, lane = t & 63;
    int s = gstart[g], cnt = counts[g];
    float ax = 0.f, ay = 0.f, az = 0.f, aw = 0.f;
    for (int i = s + sub; i < s + cnt; i += 4) {
        ushort4 v = *(const ushort4*)&H2[(size_t)i * 256 + lane * 4];
        ax += b2f(v.x); ay += b2f(v.y); az += b2f(v.z); aw += b2f(v.w);
    }
    red[sub][lane * 4 + 0] = ax;
    red[sub][lane * 4 + 1] = ay;
    red[sub][lane * 4 + 2] = az;
    red[sub][lane * 4 + 3] = aw;
    __syncthreads();
    float inv = 1.f / fmaxf((float)cnt, 1.f);
    pooled[(size_t)g * 256 + t] = (red[0][t] + red[1][t] + red[2][t] + red[3][t]) * inv;
}

// ---- classifier: out[g][c] = pooled[g] @ Wlin + blin ----
__global__ void k_final(const float* __restrict__ pooled, const void* __restrict__ Wlin,
                        const void* __restrict__ blin, const int* __restrict__ flags,
                        void* __restrict__ outv) {
    __shared__ float p[HID];
    int g = blockIdx.x, t = threadIdx.x, fb = flags[1];
    p[t] = pooled[(size_t)g * HID + t];
    __syncthreads();
    if (t < N_CLS) {
        float s = LF(blin, t, fb);
        for (int f = 0; f < HID; ++f) s = fmaf(p[f], LF(Wlin, f * N_CLS + t, fb), s);
        if (fb) ((bf16*)outv)[g * N_CLS + t] = __float2bfloat16(s);
        else    ((float*)outv)[g * N_CLS + t] = s;
    }
}

extern "C" void kernel_launch(void* const* d_in, const int* in_sizes, int n_in,
                              void* d_out, int out_size, void* d_ws, size_t ws_size,
                              hipStream_t stream) {
    (void)n_in; (void)ws_size; (void)in_sizes; (void)out_size;
    const void* x     = d_in[0];
    const int*  ei    = (const int*)d_in[1];
    const int*  batch = (const int*)d_in[2];
    const void* W1    = d_in[3];
    const void* b1    = d_in[4];
    const void* W2    = d_in[5];
    const void* b2    = d_in[6];
    const void* Wl    = d_in[7];
    const void* bl    = d_in[8];

    const int N = N_NODES, E = N_EDGES, F = IN_F, H = HID, G = N_GRAPH;

    char* ws = (char*)d_ws;
    size_t off = 0;
    auto alloc = [&](size_t bytes) -> void* {
        void* p = ws + off;
        off += (bytes + 511) & ~(size_t)511;
        return p;
    };
    unsigned short* xb   = (unsigned short*)alloc((size_t)N * F * 2);  // x in bf16
    unsigned short* bufP = (unsigned short*)alloc((size_t)N * H * 2);  // XW1, later XW2
    unsigned short* bufQ = (unsigned short*)alloc((size_t)N * H * 2);  // H1, later H2
    unsigned short* w1t  = (unsigned short*)alloc((size_t)H * F * 2);  // W1^T bf16
    unsigned short* w2t  = (unsigned short*)alloc((size_t)H * H * 2);  // W2^T bf16
    float* pooled  = (float*)alloc((size_t)G * H * 4);
    int*   deg     = (int*)alloc((size_t)N * 4);   // zero region start
    int*   cursor  = (int*)alloc((size_t)N * 4);
    int*   counts  = (int*)alloc((size_t)G * 4);   // zero region end (inclusive)
    int*   total   = (int*)alloc(512);
    int*   gstart  = (int*)alloc((size_t)G * 4);
    float* dinv    = (float*)alloc((size_t)N * 4);
    int*   rowptr  = (int*)alloc((size_t)(N + 1) * 4);
    int*   blockSum = (int*)alloc(256 * 4);
    int*   blockOff = (int*)alloc(256 * 4);
    int*   flags   = (int*)alloc(512);
    int*   col     = (int*)alloc((size_t)E * 4);
    size_t zero_bytes = (size_t)((char*)total - (char*)deg);

    hipMemsetAsync(deg, 0, zero_bytes, stream);

    int nbE = (E + 255) / 256;
    int nbN = (N + 255) / 256;

    k_detect_i<<<1, 256, 0, stream>>>(ei, flags);
    k_detect_f<<<1, 256, 0, stream>>>((const unsigned short*)x, flags);
    k_deg<<<nbE, 256, 0, stream>>>(ei, deg, flags, E, N);
    k_dinv<<<nbN, 256, 0, stream>>>(deg, dinv, batch, counts, flags, N, G);
    k_scan1<<<nbN, 256, 0, stream>>>(deg, rowptr, blockSum, N);
    k_scan2<<<1, 256, 0, stream>>>(blockSum, blockOff, total, nbN);
    k_scan3<<<nbN, 256, 0, stream>>>(rowptr, blockOff, N, total);
    k_fill<<<nbE, 256, 0, stream>>>(ei, rowptr, cursor, col, flags, E, N);
    k_scang<<<1, 256, 0, stream>>>(counts, gstart);

    // bf16 conversions
    k_cvt4<<<(N * F / 4 + 255) / 256, 256, 0, stream>>>(x, xb, flags, N * F / 4);
    k_cvtT<<<(F * 256 + 255) / 256, 256, 0, stream>>>(W1, w1t, flags, F, 7);
    k_cvtT<<<(H * 256 + 255) / 256, 256, 0, stream>>>(W2, w2t, flags, H, 8);

    int gemmGrid = (N + 63) / 64;
    int nbAgg = (N + 3) / 4;

    // layer 1
    k_gemm<<<gemmGrid, 256, 0, stream>>>(xb, w1t, bufP, N, F);
    k_agg<<<nbAgg, 256, 0, stream>>>(bufP, rowptr, col, dinv, b1, flags, bufQ, N, 1);
    // layer 2
    k_gemm<<<gemmGrid, 256, 0, stream>>>(bufQ, w2t, bufP, N, H);
    k_agg<<<nbAgg, 256, 0, stream>>>(bufP, rowptr, col, dinv, b2, flags, bufQ, N, 0);
    // pool + classify
    k_pool<<<G, 256, 0, stream>>>(bufQ, gstart, counts, pooled);
    k_final<<<G, 256, 0, stream>>>(pooled, Wl, bl, flags, d_out);
}

// Round 5
// 471.211 us; speedup vs baseline: 2.1258x; 1.1347x over previous
//
#include <hip/hip_runtime.h>
#include <hip/hip_bf16.h>

typedef __hip_bfloat16 bf16;
typedef __attribute__((ext_vector_type(8))) short short8;
typedef __attribute__((ext_vector_type(4))) float f32x4;

// ---- problem constants (fixed by reference file) ----
#define N_NODES 50000
#define N_EDGES 800000
#define IN_F    128
#define HID     256
#define N_CLS   10
#define N_GRAPH 256

// flags[0] = ints are int64 (read low words), flags[1] = floats are bf16
__device__ __forceinline__ int IG(const int* __restrict__ p, int i, int w) {
    return w ? p[2 * i] : p[i];
}
__device__ __forceinline__ float LF(const void* __restrict__ p, int i, int isbf) {
    return isbf ? __bfloat162float(((const bf16*)p)[i]) : ((const float*)p)[i];
}
__device__ __forceinline__ float b2f(unsigned short h) {
    union { unsigned u; float f; } c; c.u = ((unsigned)h) << 16; return c.f;
}
__device__ __forceinline__ unsigned short f2b(float x) {
    bf16 h = __float2bfloat16(x);
    union { bf16 b; unsigned short u; } c; c.b = h; return c.u;
}

// ---- int width detector: odd int32 words all zero -> int64 ----
__global__ __launch_bounds__(256) void k_detect_i(const int* __restrict__ ei, int* __restrict__ flags) {
    __shared__ int nz;
    if (threadIdx.x == 0) nz = 0;
    __syncthreads();
    int found = 0;
    for (int s = 0; s < 4; ++s) {
        int idx = 2 * (threadIdx.x * 4 + s) + 1;
        if (ei[idx] != 0) found = 1;
    }
    if (found) atomicAdd(&nz, 1);
    __syncthreads();
    if (threadIdx.x == 0) flags[0] = (nz == 0) ? 1 : 0;
}

// ---- float width detector on x ----
__global__ __launch_bounds__(256) void k_detect_f(const unsigned short* __restrict__ x,
                                                  int* __restrict__ flags) {
    __shared__ int cnt;
    if (threadIdx.x == 0) cnt = 0;
    __syncthreads();
    int c = 0;
    for (int s = 0; s < 8; ++s) {
        unsigned short h = x[threadIdx.x * 8 + s];
        int e = (h >> 7) & 0xFF;
        if (e >= 110 && e <= 135) c++;
    }
    atomicAdd(&cnt, c);
    __syncthreads();
    if (threadIdx.x == 0) flags[1] = (cnt > 1536) ? 1 : 0;
}

// ---- degree count over dst ----
__global__ __launch_bounds__(256) void k_deg(const int* __restrict__ ei, int* __restrict__ deg,
                                             const int* __restrict__ flags, int E, int N) {
    int e = blockIdx.x * 256 + threadIdx.x;
    int w = flags[0];
    if (e < E) {
        int d = IG(ei, E + e, w);
        int s = IG(ei, e, w);
        if ((unsigned)d < (unsigned)N && (unsigned)s < (unsigned)N)
            atomicAdd(&deg[d], 1);
    }
}

__global__ __launch_bounds__(256) void k_dinv(const int* __restrict__ deg, float* __restrict__ dinv,
                                              const int* __restrict__ batch, int* __restrict__ counts,
                                              const int* __restrict__ flags, int N, int G) {
    int i = blockIdx.x * 256 + threadIdx.x;
    int w = flags[0];
    if (i < N) {
        dinv[i] = rsqrtf((float)(deg[i] + 1));  // +1 self loop
        int g = IG(batch, i, w);
        if ((unsigned)g < (unsigned)G) atomicAdd(&counts[g], 1);
    }
}

// ---- exclusive scan over degrees ----
__global__ __launch_bounds__(256) void k_scan1(const int* __restrict__ deg, int* __restrict__ rowptr,
                                               int* __restrict__ blockSum, int N) {
    __shared__ int s[256];
    int t = threadIdx.x;
    int i = blockIdx.x * 256 + t;
    int v = (i < N) ? deg[i] : 0;
    s[t] = v;
    __syncthreads();
    for (int off = 1; off < 256; off <<= 1) {
        int add = (t >= off) ? s[t - off] : 0;
        __syncthreads();
        s[t] += add;
        __syncthreads();
    }
    if (i < N) rowptr[i] = s[t] - v;
    if (t == 255) blockSum[blockIdx.x] = s[t];
}

__global__ __launch_bounds__(256) void k_scan2(const int* __restrict__ blockSum, int* __restrict__ blockOff,
                                               int* __restrict__ total, int nb) {
    __shared__ int s[256];
    int t = threadIdx.x;
    int v = (t < nb) ? blockSum[t] : 0;
    s[t] = v;
    __syncthreads();
    for (int off = 1; off < 256; off <<= 1) {
        int add = (t >= off) ? s[t - off] : 0;
        __syncthreads();
        s[t] += add;
        __syncthreads();
    }
    blockOff[t] = s[t] - v;
    if (t == 255) total[0] = s[255];
}

__global__ __launch_bounds__(256) void k_scan3(int* __restrict__ rowptr, const int* __restrict__ blockOff,
                                               int N, const int* __restrict__ total) {
    int i = blockIdx.x * 256 + threadIdx.x;
    if (i < N) rowptr[i] += blockOff[blockIdx.x];
    if (i == 0) rowptr[N] = total[0];
}

// exclusive scan of per-graph counts -> gstart (single block, G==256)
__global__ __launch_bounds__(256) void k_scang(const int* __restrict__ counts, int* __restrict__ gstart) {
    __shared__ int s[256];
    int t = threadIdx.x;
    int v = counts[t];
    s[t] = v;
    __syncthreads();
    for (int off = 1; off < 256; off <<= 1) {
        int add = (t >= off) ? s[t - off] : 0;
        __syncthreads();
        s[t] += add;
        __syncthreads();
    }
    gstart[t] = s[t] - v;
}

// ---- CSR fill ----
__global__ __launch_bounds__(256) void k_fill(const int* __restrict__ ei, const int* __restrict__ rowptr,
                                              int* __restrict__ cursor, int* __restrict__ col,
                                              const int* __restrict__ flags, int E, int N) {
    int e = blockIdx.x * 256 + threadIdx.x;
    int w = flags[0];
    if (e < E) {
        int d = IG(ei, E + e, w);
        int s = IG(ei, e, w);
        if ((unsigned)d < (unsigned)N && (unsigned)s < (unsigned)N) {
            int pos = atomicAdd(&cursor[d], 1);
            col[rowptr[d] + pos] = s;
        }
    }
}

// ---- convert x (fp32 or bf16) to bf16 PRE-SCALED by dinv[row]: xs[i] = x[i]*dinv[i] ----
// thread handles 4 features; IN_F == 128 -> row = gid >> 5
__global__ __launch_bounds__(256) void k_cvtx(const void* __restrict__ x, const float* __restrict__ dinv,
                                              unsigned short* __restrict__ out, const int* __restrict__ flags,
                                              int n4) {
    int gid = blockIdx.x * 256 + threadIdx.x;
    if (gid >= n4) return;
    int row = gid >> 5;
    float d = dinv[row];
    int base = gid * 4;
    ushort4 o;
    if (flags[1]) {
        ushort4 v = ((const ushort4*)x)[gid];
        o.x = f2b(b2f(v.x) * d); o.y = f2b(b2f(v.y) * d);
        o.z = f2b(b2f(v.z) * d); o.w = f2b(b2f(v.w) * d);
    } else {
        float4 v = ((const float4*)x)[gid];
        o.x = f2b(v.x * d); o.y = f2b(v.y * d);
        o.z = f2b(v.z * d); o.w = f2b(v.w * d);
    }
    ((ushort4*)out)[gid] = o;
    (void)base;
}

// ---- convert + transpose weight W[K x 256] -> Wt[256 x K] bf16 ----
__global__ __launch_bounds__(256) void k_cvtT(const void* __restrict__ in, unsigned short* __restrict__ out,
                                              const int* __restrict__ flags, int K, int kshift) {
    int i = blockIdx.x * 256 + threadIdx.x;  // output index, [n][k]
    if (i >= K * 256) return;
    int n = i >> kshift;
    int k = i & (K - 1);
    out[i] = f2b(LF(in, k * 256 + n, flags[1]));
}

// ---- bf16 MFMA GEMM: C[M x 256] = A[M x K] @ B[K x 256] with fused epilogue ----
// epilogue: v = acc * (rowscale ? rowscale[row] : 1) + (bias ? bias[col] : 0); if relu: max(0)
__global__ __launch_bounds__(256) void k_gemm(const unsigned short* __restrict__ A,
                                              const unsigned short* __restrict__ Bt,
                                              unsigned short* __restrict__ C, int M, int K,
                                              const float* __restrict__ rowscale,
                                              const void* __restrict__ bias,
                                              const int* __restrict__ flags, int relu) {
    __shared__ unsigned short As[64 * 40];
    __shared__ unsigned short Bs[256 * 40];
    int t = threadIdx.x;
    int lane = t & 63;
    int w = t >> 6;
    int wr = w >> 1, wc = w & 1;
    int bm = blockIdx.x * 64;
    int l15 = lane & 15, quad = lane >> 4;
    f32x4 acc[2][8];
#pragma unroll
    for (int i = 0; i < 2; ++i)
#pragma unroll
        for (int j = 0; j < 8; ++j) acc[i][j] = (f32x4){0.f, 0.f, 0.f, 0.f};

    for (int k0 = 0; k0 < K; k0 += 32) {
        {   // stage A: 64 rows x 32 k
            int m = t >> 2, c = t & 3;
            int gm = bm + m;
            uint4 v = make_uint4(0u, 0u, 0u, 0u);
            if (gm < M) v = *(const uint4*)&A[(size_t)gm * K + k0 + c * 8];
            *(uint4*)&As[m * 40 + c * 8] = v;
        }
#pragma unroll
        for (int i = 0; i < 4; ++i) {  // stage B: 256 n x 32 k
            int cid = t + 256 * i;
            int n = cid >> 2, c = cid & 3;
            uint4 v = *(const uint4*)&Bt[(size_t)n * K + k0 + c * 8];
            *(uint4*)&Bs[n * 40 + c * 8] = v;
        }
        __syncthreads();
        short8 a0 = *(const short8*)&As[(wr * 32 + l15) * 40 + quad * 8];
        short8 a1 = *(const short8*)&As[(wr * 32 + 16 + l15) * 40 + quad * 8];
#pragma unroll
        for (int tt = 0; tt < 8; ++tt) {
            short8 b = *(const short8*)&Bs[(wc * 128 + tt * 16 + l15) * 40 + quad * 8];
            acc[0][tt] = __builtin_amdgcn_mfma_f32_16x16x32_bf16(a0, b, acc[0][tt], 0, 0, 0);
            acc[1][tt] = __builtin_amdgcn_mfma_f32_16x16x32_bf16(a1, b, acc[1][tt], 0, 0, 0);
        }
        __syncthreads();
    }
    int fb = flags[1];
    float drow[2][4];
#pragma unroll
    for (int sa = 0; sa < 2; ++sa)
#pragma unroll
        for (int r = 0; r < 4; ++r) {
            int row = bm + wr * 32 + sa * 16 + quad * 4 + r;
            drow[sa][r] = (rowscale && row < M) ? rowscale[row] : 1.f;
        }
    float bcol[8];
#pragma unroll
    for (int tt = 0; tt < 8; ++tt)
        bcol[tt] = bias ? LF(bias, wc * 128 + tt * 16 + l15, fb) : 0.f;
    // C/D layout: col = lane&15, row = quad*4 + r
#pragma unroll
    for (int sa = 0; sa < 2; ++sa)
#pragma unroll
        for (int tt = 0; tt < 8; ++tt)
#pragma unroll
            for (int r = 0; r < 4; ++r) {
                int row = bm + wr * 32 + sa * 16 + quad * 4 + r;
                int colc = wc * 128 + tt * 16 + l15;
                if (row < M) {
                    float v = fmaf(acc[sa][tt][r], drow[sa][r], bcol[tt]);
                    if (relu) v = fmaxf(v, 0.f);
                    C[(size_t)row * 256 + colc] = f2b(v);
                }
            }
}

// ---- agg over 128-feat prescaled rows: out[i] = sum_nb xs[c] + xs[i] ----
// one wave per node, lane = 2 features; 4-edge unrolled prefetch for MLP
__global__ __launch_bounds__(256) void k_agg2(const unsigned short* __restrict__ XS,
                                              const int* __restrict__ rowptr, const int* __restrict__ col,
                                              unsigned short* __restrict__ Hout, int N) {
    int lane = threadIdx.x & 63;
    int i = (blockIdx.x * 256 + threadIdx.x) >> 6;
    if (i >= N) return;
    int fo = lane * 2;
    ushort2 sv = *(const ushort2*)&XS[(size_t)i * 128 + fo];
    float ax = b2f(sv.x), ay = b2f(sv.y);
    int s = rowptr[i], e = rowptr[i + 1];
    int j = s;
    for (; j + 4 <= e; j += 4) {
        int c0 = col[j], c1 = col[j + 1], c2 = col[j + 2], c3 = col[j + 3];
        ushort2 v0 = *(const ushort2*)&XS[(size_t)c0 * 128 + fo];
        ushort2 v1 = *(const ushort2*)&XS[(size_t)c1 * 128 + fo];
        ushort2 v2 = *(const ushort2*)&XS[(size_t)c2 * 128 + fo];
        ushort2 v3 = *(const ushort2*)&XS[(size_t)c3 * 128 + fo];
        ax += b2f(v0.x) + b2f(v1.x) + b2f(v2.x) + b2f(v3.x);
        ay += b2f(v0.y) + b2f(v1.y) + b2f(v2.y) + b2f(v3.y);
    }
    for (; j < e; ++j) {
        int c = col[j];
        ushort2 v = *(const ushort2*)&XS[(size_t)c * 128 + fo];
        ax += b2f(v.x); ay += b2f(v.y);
    }
    ushort2 o;
    o.x = f2b(ax); o.y = f2b(ay);
    *(ushort2*)&Hout[(size_t)i * 128 + fo] = o;
}

// ---- agg over 256-feat prescaled rows with scale+bias epilogue ----
// out[i] = dinv[i]*(sum_nb XW[c] + XW[i]) + bias; one wave per node, lane = 4 feats
__global__ __launch_bounds__(256) void k_agg4(const unsigned short* __restrict__ XW,
                                              const int* __restrict__ rowptr, const int* __restrict__ col,
                                              const float* __restrict__ dinv, const void* __restrict__ bias,
                                              const int* __restrict__ flags,
                                              unsigned short* __restrict__ Hout, int N) {
    int lane = threadIdx.x & 63;
    int i = (blockIdx.x * 256 + threadIdx.x) >> 6;
    if (i >= N) return;
    int fo = lane * 4;
    ushort4 sv = *(const ushort4*)&XW[(size_t)i * 256 + fo];
    float ax = b2f(sv.x), ay = b2f(sv.y), az = b2f(sv.z), aw = b2f(sv.w);
    int s = rowptr[i], e = rowptr[i + 1];
    int j = s;
    for (; j + 4 <= e; j += 4) {
        int c0 = col[j], c1 = col[j + 1], c2 = col[j + 2], c3 = col[j + 3];
        ushort4 v0 = *(const ushort4*)&XW[(size_t)c0 * 256 + fo];
        ushort4 v1 = *(const ushort4*)&XW[(size_t)c1 * 256 + fo];
        ushort4 v2 = *(const ushort4*)&XW[(size_t)c2 * 256 + fo];
        ushort4 v3 = *(const ushort4*)&XW[(size_t)c3 * 256 + fo];
        ax += b2f(v0.x) + b2f(v1.x) + b2f(v2.x) + b2f(v3.x);
        ay += b2f(v0.y) + b2f(v1.y) + b2f(v2.y) + b2f(v3.y);
        az += b2f(v0.z) + b2f(v1.z) + b2f(v2.z) + b2f(v3.z);
        aw += b2f(v0.w) + b2f(v1.w) + b2f(v2.w) + b2f(v3.w);
    }
    for (; j < e; ++j) {
        int c = col[j];
        ushort4 v = *(const ushort4*)&XW[(size_t)c * 256 + fo];
        ax += b2f(v.x); ay += b2f(v.y); az += b2f(v.z); aw += b2f(v.w);
    }
    int fb = flags[1];
    float di = dinv[i];
    float bx = LF(bias, fo + 0, fb), by = LF(bias, fo + 1, fb);
    float bz = LF(bias, fo + 2, fb), bw = LF(bias, fo + 3, fb);
    ushort4 o;
    o.x = f2b(fmaf(ax, di, bx)); o.y = f2b(fmaf(ay, di, by));
    o.z = f2b(fmaf(az, di, bz)); o.w = f2b(fmaf(aw, di, bw));
    *(ushort4*)&Hout[(size_t)i * 256 + fo] = o;
}

// ---- segment-mean pool over sorted batch ranges: one block per graph ----
__global__ __launch_bounds__(256) void k_pool(const unsigned short* __restrict__ H2,
                                              const int* __restrict__ gstart, const int* __restrict__ counts,
                                              float* __restrict__ pooled) {
    __shared__ float red[4][256];
    int g = blockIdx.x, t = threadIdx.x;
    int sub = t >> 6, lane = t & 63;
    int s = gstart[g], cnt = counts[g];
    float ax = 0.f, ay = 0.f, az = 0.f, aw = 0.f;
    for (int i = s + sub; i < s + cnt; i += 4) {
        ushort4 v = *(const ushort4*)&H2[(size_t)i * 256 + lane * 4];
        ax += b2f(v.x); ay += b2f(v.y); az += b2f(v.z); aw += b2f(v.w);
    }
    red[sub][lane * 4 + 0] = ax;
    red[sub][lane * 4 + 1] = ay;
    red[sub][lane * 4 + 2] = az;
    red[sub][lane * 4 + 3] = aw;
    __syncthreads();
    float inv = 1.f / fmaxf((float)cnt, 1.f);
    pooled[(size_t)g * 256 + t] = (red[0][t] + red[1][t] + red[2][t] + red[3][t]) * inv;
}

// ---- classifier: out[g][c] = pooled[g] @ Wlin + blin ----
__global__ void k_final(const float* __restrict__ pooled, const void* __restrict__ Wlin,
                        const void* __restrict__ blin, const int* __restrict__ flags,
                        void* __restrict__ outv) {
    __shared__ float p[HID];
    int g = blockIdx.x, t = threadIdx.x, fb = flags[1];
    p[t] = pooled[(size_t)g * HID + t];
    __syncthreads();
    if (t < N_CLS) {
        float s = LF(blin, t, fb);
        for (int f = 0; f < HID; ++f) s = fmaf(p[f], LF(Wlin, f * N_CLS + t, fb), s);
        if (fb) ((bf16*)outv)[g * N_CLS + t] = __float2bfloat16(s);
        else    ((float*)outv)[g * N_CLS + t] = s;
    }
}

extern "C" void kernel_launch(void* const* d_in, const int* in_sizes, int n_in,
                              void* d_out, int out_size, void* d_ws, size_t ws_size,
                              hipStream_t stream) {
    (void)n_in; (void)ws_size; (void)in_sizes; (void)out_size;
    const void* x     = d_in[0];
    const int*  ei    = (const int*)d_in[1];
    const int*  batch = (const int*)d_in[2];
    const void* W1    = d_in[3];
    const void* b1    = d_in[4];
    const void* W2    = d_in[5];
    const void* b2    = d_in[6];
    const void* Wl    = d_in[7];
    const void* bl    = d_in[8];

    const int N = N_NODES, E = N_EDGES, F = IN_F, H = HID, G = N_GRAPH;

    char* ws = (char*)d_ws;
    size_t off = 0;
    auto alloc = [&](size_t bytes) -> void* {
        void* p = ws + off;
        off += (bytes + 511) & ~(size_t)511;
        return p;
    };
    unsigned short* xs   = (unsigned short*)alloc((size_t)N * F * 2);  // prescaled x, bf16 (12.8 MB)
    unsigned short* aggX = (unsigned short*)alloc((size_t)N * F * 2);  // A_norm-partial @ x  (12.8 MB)
    unsigned short* H1   = (unsigned short*)alloc((size_t)N * H * 2);  // layer-1 out (25.6 MB)
    unsigned short* H2   = (unsigned short*)alloc((size_t)N * H * 2);  // layer-2 out (25.6 MB)
    // XW2s aliases xs+aggX (contiguous 25.6 MB; both dead after GEMM1 consumes aggX)
    unsigned short* XW2s = xs;
    unsigned short* w1t  = (unsigned short*)alloc((size_t)H * F * 2);  // W1^T bf16
    unsigned short* w2t  = (unsigned short*)alloc((size_t)H * H * 2);  // W2^T bf16
    float* pooled  = (float*)alloc((size_t)G * H * 4);
    int*   deg     = (int*)alloc((size_t)N * 4);   // zero region start
    int*   cursor  = (int*)alloc((size_t)N * 4);
    int*   counts  = (int*)alloc((size_t)G * 4);   // zero region end
    int*   total   = (int*)alloc(512);
    int*   gstart  = (int*)alloc((size_t)G * 4);
    float* dinv    = (float*)alloc((size_t)N * 4);
    int*   rowptr  = (int*)alloc((size_t)(N + 1) * 4);
    int*   blockSum = (int*)alloc(256 * 4);
    int*   blockOff = (int*)alloc(256 * 4);
    int*   flags   = (int*)alloc(512);
    int*   col     = (int*)alloc((size_t)E * 4);
    size_t zero_bytes = (size_t)((char*)total - (char*)deg);

    hipMemsetAsync(deg, 0, zero_bytes, stream);

    int nbE = (E + 255) / 256;
    int nbN = (N + 255) / 256;

    k_detect_i<<<1, 256, 0, stream>>>(ei, flags);
    k_detect_f<<<1, 256, 0, stream>>>((const unsigned short*)x, flags);
    k_deg<<<nbE, 256, 0, stream>>>(ei, deg, flags, E, N);
    k_dinv<<<nbN, 256, 0, stream>>>(deg, dinv, batch, counts, flags, N, G);
    k_scan1<<<nbN, 256, 0, stream>>>(deg, rowptr, blockSum, N);
    k_scan2<<<1, 256, 0, stream>>>(blockSum, blockOff, total, nbN);
    k_scan3<<<nbN, 256, 0, stream>>>(rowptr, blockOff, N, total);
    k_fill<<<nbE, 256, 0, stream>>>(ei, rowptr, cursor, col, flags, E, N);
    k_scang<<<1, 256, 0, stream>>>(counts, gstart);

    // conversions: prescaled x, transposed weights
    k_cvtx<<<(N * F / 4 + 255) / 256, 256, 0, stream>>>(x, dinv, xs, flags, N * F / 4);
    k_cvtT<<<(F * 256 + 255) / 256, 256, 0, stream>>>(W1, w1t, flags, F, 7);
    k_cvtT<<<(H * 256 + 255) / 256, 256, 0, stream>>>(W2, w2t, flags, H, 8);

    int gemmGrid = (N + 63) / 64;
    int nbAgg = (N + 3) / 4;

    // layer 1: aggregate raw features (256B rows), then GEMM with dinv-scale + bias + relu
    k_agg2<<<nbAgg, 256, 0, stream>>>(xs, rowptr, col, aggX, N);
    k_gemm<<<gemmGrid, 256, 0, stream>>>(aggX, w1t, H1, N, F, dinv, b1, flags, 1);
    // layer 2: GEMM with dinv-scale epilogue, then aggregate + scale + bias
    k_gemm<<<gemmGrid, 256, 0, stream>>>(H1, w2t, XW2s, N, H, dinv, nullptr, flags, 0);
    k_agg4<<<nbAgg, 256, 0, stream>>>(XW2s, rowptr, col, dinv, b2, flags, H2, N);
    // pool + classify
    k_pool<<<G, 256, 0, stream>>>(H2, gstart, counts, pooled);
    k_final<<<G, 256, 0, stream>>>(pooled, Wl, bl, flags, d_out);
}

// Round 6
// 402.813 us; speedup vs baseline: 2.4867x; 1.1698x over previous
//
#include <hip/hip_runtime.h>
#include <hip/hip_bf16.h>

typedef __hip_bfloat16 bf16;
typedef __attribute__((ext_vector_type(8))) short short8;
typedef __attribute__((ext_vector_type(4))) float f32x4;

// ---- problem constants (fixed by reference file) ----
#define N_NODES 50000
#define N_EDGES 800000
#define IN_F    128
#define HID     256
#define N_CLS   10
#define N_GRAPH 256

// flags[0] = ints are int64 (read low words), flags[1] = floats are bf16
__device__ __forceinline__ int IG(const int* __restrict__ p, int i, int w) {
    return w ? p[2 * i] : p[i];
}
__device__ __forceinline__ float LF(const void* __restrict__ p, int i, int isbf) {
    return isbf ? __bfloat162float(((const bf16*)p)[i]) : ((const float*)p)[i];
}
__device__ __forceinline__ float b2f(unsigned short h) {
    union { unsigned u; float f; } c; c.u = ((unsigned)h) << 16; return c.f;
}
__device__ __forceinline__ unsigned short f2b(float x) {
    bf16 h = __float2bfloat16(x);
    union { bf16 b; unsigned short u; } c; c.b = h; return c.u;
}

// ---- int width detector: odd int32 words all zero -> int64 ----
__global__ __launch_bounds__(256) void k_detect_i(const int* __restrict__ ei, int* __restrict__ flags) {
    __shared__ int nz;
    if (threadIdx.x == 0) nz = 0;
    __syncthreads();
    int found = 0;
    for (int s = 0; s < 4; ++s) {
        int idx = 2 * (threadIdx.x * 4 + s) + 1;
        if (ei[idx] != 0) found = 1;
    }
    if (found) atomicAdd(&nz, 1);
    __syncthreads();
    if (threadIdx.x == 0) flags[0] = (nz == 0) ? 1 : 0;
}

// ---- float width detector on x ----
__global__ __launch_bounds__(256) void k_detect_f(const unsigned short* __restrict__ x,
                                                  int* __restrict__ flags) {
    __shared__ int cnt;
    if (threadIdx.x == 0) cnt = 0;
    __syncthreads();
    int c = 0;
    for (int s = 0; s < 8; ++s) {
        unsigned short h = x[threadIdx.x * 8 + s];
        int e = (h >> 7) & 0xFF;
        if (e >= 110 && e <= 135) c++;
    }
    atomicAdd(&cnt, c);
    __syncthreads();
    if (threadIdx.x == 0) flags[1] = (cnt > 1536) ? 1 : 0;
}

// ---- degree count over dst ----
__global__ __launch_bounds__(256) void k_deg(const int* __restrict__ ei, int* __restrict__ deg,
                                             const int* __restrict__ flags, int E, int N) {
    int e = blockIdx.x * 256 + threadIdx.x;
    int w = flags[0];
    if (e < E) {
        int d = IG(ei, E + e, w);
        int s = IG(ei, e, w);
        if ((unsigned)d < (unsigned)N && (unsigned)s < (unsigned)N)
            atomicAdd(&deg[d], 1);
    }
}

// ---- dinv: pure elementwise (no atomics) ----
__global__ __launch_bounds__(256) void k_dinv(const int* __restrict__ deg, float* __restrict__ dinv, int N) {
    int i = blockIdx.x * 256 + threadIdx.x;
    if (i < N) dinv[i] = rsqrtf((float)(deg[i] + 1));  // +1 self loop
}

// ---- graph segment boundaries from SORTED batch: gstart[g] = first i with batch[i] >= g ----
// gstart has G+1 entries; total writes across grid = G+1 (no atomics).
__global__ __launch_bounds__(256) void k_bound(const int* __restrict__ batch, const int* __restrict__ flags,
                                               int* __restrict__ gstart, int N, int G) {
    int i = blockIdx.x * 256 + threadIdx.x;
    if (i > N) return;
    int w = flags[0];
    int prev = (i == 0) ? -1 : IG(batch, i - 1, w);
    int cur  = (i == N) ? G : IG(batch, i, w);
    if (prev < -1) prev = -1;
    if (cur > G) cur = G;
    for (int g = prev + 1; g <= cur; ++g)
        if (g >= 0 && g <= G) gstart[g] = i;
}

// ---- exclusive scan over degrees ----
__global__ __launch_bounds__(256) void k_scan1(const int* __restrict__ deg, int* __restrict__ rowptr,
                                               int* __restrict__ blockSum, int N) {
    __shared__ int s[256];
    int t = threadIdx.x;
    int i = blockIdx.x * 256 + t;
    int v = (i < N) ? deg[i] : 0;
    s[t] = v;
    __syncthreads();
    for (int off = 1; off < 256; off <<= 1) {
        int add = (t >= off) ? s[t - off] : 0;
        __syncthreads();
        s[t] += add;
        __syncthreads();
    }
    if (i < N) rowptr[i] = s[t] - v;
    if (t == 255) blockSum[blockIdx.x] = s[t];
}

__global__ __launch_bounds__(256) void k_scan2(const int* __restrict__ blockSum, int* __restrict__ blockOff,
                                               int* __restrict__ total, int nb) {
    __shared__ int s[256];
    int t = threadIdx.x;
    int v = (t < nb) ? blockSum[t] : 0;
    s[t] = v;
    __syncthreads();
    for (int off = 1; off < 256; off <<= 1) {
        int add = (t >= off) ? s[t - off] : 0;
        __syncthreads();
        s[t] += add;
        __syncthreads();
    }
    blockOff[t] = s[t] - v;
    if (t == 255) total[0] = s[255];
}

__global__ __launch_bounds__(256) void k_scan3(int* __restrict__ rowptr, const int* __restrict__ blockOff,
                                               int N, const int* __restrict__ total) {
    int i = blockIdx.x * 256 + threadIdx.x;
    if (i < N) rowptr[i] += blockOff[blockIdx.x];
    if (i == 0) rowptr[N] = total[0];
}

// ---- CSR fill ----
__global__ __launch_bounds__(256) void k_fill(const int* __restrict__ ei, const int* __restrict__ rowptr,
                                              int* __restrict__ cursor, int* __restrict__ col,
                                              const int* __restrict__ flags, int E, int N) {
    int e = blockIdx.x * 256 + threadIdx.x;
    int w = flags[0];
    if (e < E) {
        int d = IG(ei, E + e, w);
        int s = IG(ei, e, w);
        if ((unsigned)d < (unsigned)N && (unsigned)s < (unsigned)N) {
            int pos = atomicAdd(&cursor[d], 1);
            col[rowptr[d] + pos] = s;
        }
    }
}

// ---- convert x to bf16 PRE-SCALED by dinv[row]: xs[i] = x[i]*dinv[i] ----
__global__ __launch_bounds__(256) void k_cvtx(const void* __restrict__ x, const float* __restrict__ dinv,
                                              unsigned short* __restrict__ out, const int* __restrict__ flags,
                                              int n4) {
    int gid = blockIdx.x * 256 + threadIdx.x;
    if (gid >= n4) return;
    int row = gid >> 5;  // IN_F/4 == 32 chunks per row
    float d = dinv[row];
    ushort4 o;
    if (flags[1]) {
        ushort4 v = ((const ushort4*)x)[gid];
        o.x = f2b(b2f(v.x) * d); o.y = f2b(b2f(v.y) * d);
        o.z = f2b(b2f(v.z) * d); o.w = f2b(b2f(v.w) * d);
    } else {
        float4 v = ((const float4*)x)[gid];
        o.x = f2b(v.x * d); o.y = f2b(v.y * d);
        o.z = f2b(v.z * d); o.w = f2b(v.w * d);
    }
    ((ushort4*)out)[gid] = o;
}

// ---- convert + transpose weight W[K x 256] -> Wt[256 x K] bf16 ----
__global__ __launch_bounds__(256) void k_cvtT(const void* __restrict__ in, unsigned short* __restrict__ out,
                                              const int* __restrict__ flags, int K, int kshift) {
    int i = blockIdx.x * 256 + threadIdx.x;
    if (i >= K * 256) return;
    int n = i >> kshift;
    int k = i & (K - 1);
    out[i] = f2b(LF(in, k * 256 + n, flags[1]));
}

// ---- bf16 MFMA GEMM: C[M x 256] = A[M x K] @ B[K x 256] with fused epilogue ----
__global__ __launch_bounds__(256) void k_gemm(const unsigned short* __restrict__ A,
                                              const unsigned short* __restrict__ Bt,
                                              unsigned short* __restrict__ C, int M, int K,
                                              const float* __restrict__ rowscale,
                                              const void* __restrict__ bias,
                                              const int* __restrict__ flags, int relu) {
    __shared__ unsigned short As[64 * 40];
    __shared__ unsigned short Bs[256 * 40];
    int t = threadIdx.x;
    int lane = t & 63;
    int w = t >> 6;
    int wr = w >> 1, wc = w & 1;
    int bm = blockIdx.x * 64;
    int l15 = lane & 15, quad = lane >> 4;
    f32x4 acc[2][8];
#pragma unroll
    for (int i = 0; i < 2; ++i)
#pragma unroll
        for (int j = 0; j < 8; ++j) acc[i][j] = (f32x4){0.f, 0.f, 0.f, 0.f};

    for (int k0 = 0; k0 < K; k0 += 32) {
        {
            int m = t >> 2, c = t & 3;
            int gm = bm + m;
            uint4 v = make_uint4(0u, 0u, 0u, 0u);
            if (gm < M) v = *(const uint4*)&A[(size_t)gm * K + k0 + c * 8];
            *(uint4*)&As[m * 40 + c * 8] = v;
        }
#pragma unroll
        for (int i = 0; i < 4; ++i) {
            int cid = t + 256 * i;
            int n = cid >> 2, c = cid & 3;
            uint4 v = *(const uint4*)&Bt[(size_t)n * K + k0 + c * 8];
            *(uint4*)&Bs[n * 40 + c * 8] = v;
        }
        __syncthreads();
        short8 a0 = *(const short8*)&As[(wr * 32 + l15) * 40 + quad * 8];
        short8 a1 = *(const short8*)&As[(wr * 32 + 16 + l15) * 40 + quad * 8];
#pragma unroll
        for (int tt = 0; tt < 8; ++tt) {
            short8 b = *(const short8*)&Bs[(wc * 128 + tt * 16 + l15) * 40 + quad * 8];
            acc[0][tt] = __builtin_amdgcn_mfma_f32_16x16x32_bf16(a0, b, acc[0][tt], 0, 0, 0);
            acc[1][tt] = __builtin_amdgcn_mfma_f32_16x16x32_bf16(a1, b, acc[1][tt], 0, 0, 0);
        }
        __syncthreads();
    }
    int fb = flags[1];
    float drow[2][4];
#pragma unroll
    for (int sa = 0; sa < 2; ++sa)
#pragma unroll
        for (int r = 0; r < 4; ++r) {
            int row = bm + wr * 32 + sa * 16 + quad * 4 + r;
            drow[sa][r] = (rowscale && row < M) ? rowscale[row] : 1.f;
        }
    float bcol[8];
#pragma unroll
    for (int tt = 0; tt < 8; ++tt)
        bcol[tt] = bias ? LF(bias, wc * 128 + tt * 16 + l15, fb) : 0.f;
#pragma unroll
    for (int sa = 0; sa < 2; ++sa)
#pragma unroll
        for (int tt = 0; tt < 8; ++tt)
#pragma unroll
            for (int r = 0; r < 4; ++r) {
                int row = bm + wr * 32 + sa * 16 + quad * 4 + r;
                int colc = wc * 128 + tt * 16 + l15;
                if (row < M) {
                    float v = fmaf(acc[sa][tt][r], drow[sa][r], bcol[tt]);
                    if (relu) v = fmaxf(v, 0.f);
                    C[(size_t)row * 256 + colc] = f2b(v);
                }
            }
}

// ---- agg over 128-feat prescaled rows: out[i] = sum_nb xs[c] + xs[i] ----
// one wave per node, lane = 2 features; 8-edge unrolled prefetch for MLP
__global__ __launch_bounds__(256) void k_agg2(const unsigned short* __restrict__ XS,
                                              const int* __restrict__ rowptr, const int* __restrict__ col,
                                              unsigned short* __restrict__ Hout, int N) {
    int lane = threadIdx.x & 63;
    int i = (blockIdx.x * 256 + threadIdx.x) >> 6;
    if (i >= N) return;
    int fo = lane * 2;
    ushort2 sv = *(const ushort2*)&XS[(size_t)i * 128 + fo];
    float ax = b2f(sv.x), ay = b2f(sv.y);
    int s = rowptr[i], e = rowptr[i + 1];
    int j = s;
    for (; j + 8 <= e; j += 8) {
        ushort2 v0 = *(const ushort2*)&XS[(size_t)col[j + 0] * 128 + fo];
        ushort2 v1 = *(const ushort2*)&XS[(size_t)col[j + 1] * 128 + fo];
        ushort2 v2 = *(const ushort2*)&XS[(size_t)col[j + 2] * 128 + fo];
        ushort2 v3 = *(const ushort2*)&XS[(size_t)col[j + 3] * 128 + fo];
        ushort2 v4 = *(const ushort2*)&XS[(size_t)col[j + 4] * 128 + fo];
        ushort2 v5 = *(const ushort2*)&XS[(size_t)col[j + 5] * 128 + fo];
        ushort2 v6 = *(const ushort2*)&XS[(size_t)col[j + 6] * 128 + fo];
        ushort2 v7 = *(const ushort2*)&XS[(size_t)col[j + 7] * 128 + fo];
        ax += b2f(v0.x) + b2f(v1.x) + b2f(v2.x) + b2f(v3.x)
            + b2f(v4.x) + b2f(v5.x) + b2f(v6.x) + b2f(v7.x);
        ay += b2f(v0.y) + b2f(v1.y) + b2f(v2.y) + b2f(v3.y)
            + b2f(v4.y) + b2f(v5.y) + b2f(v6.y) + b2f(v7.y);
    }
    for (; j < e; ++j) {
        ushort2 v = *(const ushort2*)&XS[(size_t)col[j] * 128 + fo];
        ax += b2f(v.x); ay += b2f(v.y);
    }
    ushort2 o;
    o.x = f2b(ax); o.y = f2b(ay);
    *(ushort2*)&Hout[(size_t)i * 128 + fo] = o;
}

// ---- agg over 256-feat prescaled rows with scale+bias epilogue ----
// out[i] = dinv[i]*(sum_nb XW[c] + XW[i]) + bias; one wave per node, lane = 4 feats
__global__ __launch_bounds__(256) void k_agg4(const unsigned short* __restrict__ XW,
                                              const int* __restrict__ rowptr, const int* __restrict__ col,
                                              const float* __restrict__ dinv, const void* __restrict__ bias,
                                              const int* __restrict__ flags,
                                              unsigned short* __restrict__ Hout, int N) {
    int lane = threadIdx.x & 63;
    int i = (blockIdx.x * 256 + threadIdx.x) >> 6;
    if (i >= N) return;
    int fo = lane * 4;
    ushort4 sv = *(const ushort4*)&XW[(size_t)i * 256 + fo];
    float ax = b2f(sv.x), ay = b2f(sv.y), az = b2f(sv.z), aw = b2f(sv.w);
    int s = rowptr[i], e = rowptr[i + 1];
    int j = s;
    for (; j + 8 <= e; j += 8) {
        ushort4 v0 = *(const ushort4*)&XW[(size_t)col[j + 0] * 256 + fo];
        ushort4 v1 = *(const ushort4*)&XW[(size_t)col[j + 1] * 256 + fo];
        ushort4 v2 = *(const ushort4*)&XW[(size_t)col[j + 2] * 256 + fo];
        ushort4 v3 = *(const ushort4*)&XW[(size_t)col[j + 3] * 256 + fo];
        ushort4 v4 = *(const ushort4*)&XW[(size_t)col[j + 4] * 256 + fo];
        ushort4 v5 = *(const ushort4*)&XW[(size_t)col[j + 5] * 256 + fo];
        ushort4 v6 = *(const ushort4*)&XW[(size_t)col[j + 6] * 256 + fo];
        ushort4 v7 = *(const ushort4*)&XW[(size_t)col[j + 7] * 256 + fo];
        ax += b2f(v0.x) + b2f(v1.x) + b2f(v2.x) + b2f(v3.x)
            + b2f(v4.x) + b2f(v5.x) + b2f(v6.x) + b2f(v7.x);
        ay += b2f(v0.y) + b2f(v1.y) + b2f(v2.y) + b2f(v3.y)
            + b2f(v4.y) + b2f(v5.y) + b2f(v6.y) + b2f(v7.y);
        az += b2f(v0.z) + b2f(v1.z) + b2f(v2.z) + b2f(v3.z)
            + b2f(v4.z) + b2f(v5.z) + b2f(v6.z) + b2f(v7.z);
        aw += b2f(v0.w) + b2f(v1.w) + b2f(v2.w) + b2f(v3.w)
            + b2f(v4.w) + b2f(v5.w) + b2f(v6.w) + b2f(v7.w);
    }
    for (; j < e; ++j) {
        ushort4 v = *(const ushort4*)&XW[(size_t)col[j] * 256 + fo];
        ax += b2f(v.x); ay += b2f(v.y); az += b2f(v.z); aw += b2f(v.w);
    }
    int fb = flags[1];
    float di = dinv[i];
    float bx = LF(bias, fo + 0, fb), by = LF(bias, fo + 1, fb);
    float bz = LF(bias, fo + 2, fb), bw = LF(bias, fo + 3, fb);
    ushort4 o;
    o.x = f2b(fmaf(ax, di, bx)); o.y = f2b(fmaf(ay, di, by));
    o.z = f2b(fmaf(az, di, bz)); o.w = f2b(fmaf(aw, di, bw));
    *(ushort4*)&Hout[(size_t)i * 256 + fo] = o;
}

// ---- segment-mean pool over sorted batch ranges: one block per graph ----
__global__ __launch_bounds__(256) void k_pool(const unsigned short* __restrict__ H2,
                                              const int* __restrict__ gstart,
                                              float* __restrict__ pooled) {
    __shared__ float red[4][256];
    int g = blockIdx.x, t = threadIdx.x;
    int sub = t >> 6, lane = t & 63;
    int s = gstart[g], e = gstart[g + 1];
    int cnt = e - s;
    float ax = 0.f, ay = 0.f, az = 0.f, aw = 0.f;
    for (int i = s + sub; i < e; i += 4) {
        ushort4 v = *(const ushort4*)&H2[(size_t)i * 256 + lane * 4];
        ax += b2f(v.x); ay += b2f(v.y); az += b2f(v.z); aw += b2f(v.w);
    }
    red[sub][lane * 4 + 0] = ax;
    red[sub][lane * 4 + 1] = ay;
    red[sub][lane * 4 + 2] = az;
    red[sub][lane * 4 + 3] = aw;
    __syncthreads();
    float inv = 1.f / fmaxf((float)cnt, 1.f);
    pooled[(size_t)g * 256 + t] = (red[0][t] + red[1][t] + red[2][t] + red[3][t]) * inv;
}

// ---- classifier: out[g][c] = pooled[g] @ Wlin + blin ----
__global__ void k_final(const float* __restrict__ pooled, const void* __restrict__ Wlin,
                        const void* __restrict__ blin, const int* __restrict__ flags,
                        void* __restrict__ outv) {
    __shared__ float p[HID];
    int g = blockIdx.x, t = threadIdx.x, fb = flags[1];
    p[t] = pooled[(size_t)g * HID + t];
    __syncthreads();
    if (t < N_CLS) {
        float s = LF(blin, t, fb);
        for (int f = 0; f < HID; ++f) s = fmaf(p[f], LF(Wlin, f * N_CLS + t, fb), s);
        if (fb) ((bf16*)outv)[g * N_CLS + t] = __float2bfloat16(s);
        else    ((float*)outv)[g * N_CLS + t] = s;
    }
}

extern "C" void kernel_launch(void* const* d_in, const int* in_sizes, int n_in,
                              void* d_out, int out_size, void* d_ws, size_t ws_size,
                              hipStream_t stream) {
    (void)n_in; (void)ws_size; (void)in_sizes; (void)out_size;
    const void* x     = d_in[0];
    const int*  ei    = (const int*)d_in[1];
    const int*  batch = (const int*)d_in[2];
    const void* W1    = d_in[3];
    const void* b1    = d_in[4];
    const void* W2    = d_in[5];
    const void* b2    = d_in[6];
    const void* Wl    = d_in[7];
    const void* bl    = d_in[8];

    const int N = N_NODES, E = N_EDGES, F = IN_F, H = HID, G = N_GRAPH;

    char* ws = (char*)d_ws;
    size_t off = 0;
    auto alloc = [&](size_t bytes) -> void* {
        void* p = ws + off;
        off += (bytes + 511) & ~(size_t)511;
        return p;
    };
    unsigned short* xs   = (unsigned short*)alloc((size_t)N * F * 2);  // prescaled x, bf16
    unsigned short* aggX = (unsigned short*)alloc((size_t)N * F * 2);  // A-partial @ x
    unsigned short* H1   = (unsigned short*)alloc((size_t)N * H * 2);
    unsigned short* H2   = (unsigned short*)alloc((size_t)N * H * 2);
    unsigned short* XW2s = xs;  // aliases xs+aggX (both dead after GEMM1)
    unsigned short* w1t  = (unsigned short*)alloc((size_t)H * F * 2);
    unsigned short* w2t  = (unsigned short*)alloc((size_t)H * H * 2);
    float* pooled  = (float*)alloc((size_t)G * H * 4);
    int*   deg     = (int*)alloc((size_t)N * 4);   // zero region start
    int*   cursor  = (int*)alloc((size_t)N * 4);   // zero region end
    int*   total   = (int*)alloc(512);
    int*   gstart  = (int*)alloc((size_t)(G + 1) * 4);
    float* dinv    = (float*)alloc((size_t)N * 4);
    int*   rowptr  = (int*)alloc((size_t)(N + 1) * 4);
    int*   blockSum = (int*)alloc(256 * 4);
    int*   blockOff = (int*)alloc(256 * 4);
    int*   flags   = (int*)alloc(512);
    int*   col     = (int*)alloc((size_t)E * 4);
    size_t zero_bytes = (size_t)((char*)total - (char*)deg);

    hipMemsetAsync(deg, 0, zero_bytes, stream);

    int nbE = (E + 255) / 256;
    int nbN = (N + 255) / 256;

    k_detect_i<<<1, 256, 0, stream>>>(ei, flags);
    k_detect_f<<<1, 256, 0, stream>>>((const unsigned short*)x, flags);
    k_deg<<<nbE, 256, 0, stream>>>(ei, deg, flags, E, N);
    k_dinv<<<nbN, 256, 0, stream>>>(deg, dinv, N);
    k_bound<<<(N + 256) / 256, 256, 0, stream>>>(batch, flags, gstart, N, G);
    k_scan1<<<nbN, 256, 0, stream>>>(deg, rowptr, blockSum, N);
    k_scan2<<<1, 256, 0, stream>>>(blockSum, blockOff, total, nbN);
    k_scan3<<<nbN, 256, 0, stream>>>(rowptr, blockOff, N, total);
    k_fill<<<nbE, 256, 0, stream>>>(ei, rowptr, cursor, col, flags, E, N);

    // conversions: prescaled x, transposed weights
    k_cvtx<<<(N * F / 4 + 255) / 256, 256, 0, stream>>>(x, dinv, xs, flags, N * F / 4);
    k_cvtT<<<(F * 256 + 255) / 256, 256, 0, stream>>>(W1, w1t, flags, F, 7);
    k_cvtT<<<(H * 256 + 255) / 256, 256, 0, stream>>>(W2, w2t, flags, H, 8);

    int gemmGrid = (N + 63) / 64;
    int nbAgg = (N + 3) / 4;

    // layer 1: aggregate raw features, then GEMM with dinv-scale + bias + relu
    k_agg2<<<nbAgg, 256, 0, stream>>>(xs, rowptr, col, aggX, N);
    k_gemm<<<gemmGrid, 256, 0, stream>>>(aggX, w1t, H1, N, F, dinv, b1, flags, 1);
    // layer 2: GEMM with dinv-scale epilogue, then aggregate + scale + bias
    k_gemm<<<gemmGrid, 256, 0, stream>>>(H1, w2t, XW2s, N, H, dinv, nullptr, flags, 0);
    k_agg4<<<nbAgg, 256, 0, stream>>>(XW2s, rowptr, col, dinv, b2, flags, H2, N);
    // pool + classify
    k_pool<<<G, 256, 0, stream>>>(H2, gstart, pooled);
    k_final<<<G, 256, 0, stream>>>(pooled, Wl, bl, flags, d_out);
}